// Round 2
// baseline (14364.574 us; speedup 1.0000x reference)
//
#include <hip/hip_runtime.h>
#include <hip/hip_cooperative_groups.h>

namespace cg = cooperative_groups;

#define TT 128
#define BB 64
#define HH 2048
#define VV 10000
#define VP 10048

#define SMEM_BYTES (131072 + 8192)

typedef __attribute__((ext_vector_type(8))) short s16x8;
typedef __attribute__((ext_vector_type(4))) float f32x4;

#define MFMA(a,b,c) __builtin_amdgcn_mfma_f32_16x16x32_bf16((a),(b),(c),0,0,0)

static __device__ __forceinline__ short f2bf(float x){
  unsigned u = __float_as_uint(x);
  u += 0x7fffu + ((u>>16)&1u);
  return (short)(u>>16);
}
static __device__ __forceinline__ float bf2f(short b){
  return __uint_as_float(((unsigned)(unsigned short)b)<<16);
}

// Swizzled fragment layout for an [N,K] matrix used as MFMA B-operand (or [M,K] as A):
//   idx = ((nt*KC + kc)*64 + lane)*8 + j,  row = nt*16+(lane&15), k = kc*32+(lane>>4)*8+j
// -> a wave's fragment load is 64 lanes x 16B contiguous.

// ---------- split W0 into x-part / h-part, hi/lo bf16, swizzled (KC=64 each) ----------
__global__ __launch_bounds__(256) void k_split_w0(
    const float* __restrict__ W0,
    short* __restrict__ WxHi, short* __restrict__ WxLo,
    short* __restrict__ WhHi, short* __restrict__ WhLo){
  int tid = blockIdx.x*256 + threadIdx.x;     // 2048*512 threads
  int row = tid >> 9;
  int c8  = (tid & 511) << 3;
  const float4* s = (const float4*)(W0 + (size_t)row*4096 + c8);
  float4 f0 = s[0], f1 = s[1];
  float v[8] = {f0.x,f0.y,f0.z,f0.w,f1.x,f1.y,f1.z,f1.w};
  short hs[8], lsv[8];
#pragma unroll
  for(int j=0;j<8;j++){ hs[j]=f2bf(v[j]); lsv[j]=f2bf(v[j]-bf2f(hs[j])); }
  int isH = (c8 >= 2048);
  int k = c8 - (isH ? 2048 : 0);
  short* dh = isH ? WhHi : WxHi;
  short* dl = isH ? WhLo : WxLo;
  int nt = row>>4, kc = k>>5, ln = (row&15) | (((k>>3)&3)<<4);
  size_t base = ((size_t)(nt*64 + kc)*64 + ln)*8;
  *(s16x8*)(dh+base) = *(s16x8*)hs;
  *(s16x8*)(dl+base) = *(s16x8*)lsv;
}

// ---------- split W1 (K=4096, KC=128) ----------
__global__ __launch_bounds__(256) void k_split_w1(
    const float* __restrict__ W1,
    short* __restrict__ WHi, short* __restrict__ WLo){
  int tid = blockIdx.x*256 + threadIdx.x;
  int row = tid >> 9;
  int c8  = (tid & 511) << 3;
  const float4* s = (const float4*)(W1 + (size_t)row*4096 + c8);
  float4 f0 = s[0], f1 = s[1];
  float v[8] = {f0.x,f0.y,f0.z,f0.w,f1.x,f1.y,f1.z,f1.w};
  short hs[8], lsv[8];
#pragma unroll
  for(int j=0;j<8;j++){ hs[j]=f2bf(v[j]); lsv[j]=f2bf(v[j]-bf2f(hs[j])); }
  int nt = row>>4, kc = c8>>5, ln = (row&15) | (((c8>>3)&3)<<4);
  size_t base = ((size_t)(nt*128 + kc)*64 + ln)*8;
  *(s16x8*)(WHi+base) = *(s16x8*)hs;
  *(s16x8*)(WLo+base) = *(s16x8*)lsv;
}

// ---------- Wout -> single bf16, swizzled, zero-padded to 10048 rows ----------
__global__ __launch_bounds__(256) void k_conv_wout(
    const float* __restrict__ Wout, short* __restrict__ Wo){
  int row = blockIdx.x;             // 0..10047
  int k = threadIdx.x << 3;
  short hs[8];
  if(row < VV){
    const float4* s = (const float4*)(Wout + (size_t)row*2048 + k);
    float4 f0 = s[0], f1 = s[1];
    float v[8] = {f0.x,f0.y,f0.z,f0.w,f1.x,f1.y,f1.z,f1.w};
#pragma unroll
    for(int j=0;j<8;j++) hs[j]=f2bf(v[j]);
  } else {
#pragma unroll
    for(int j=0;j<8;j++) hs[j]=0;
  }
  int nt = row>>4, kc = k>>5, ln = (row&15) | (((k>>3)&3)<<4);
  size_t base = ((size_t)(nt*64 + kc)*64 + ln)*8;
  *(s16x8*)(Wo+base) = *(s16x8*)hs;
}

// ---------- init h state from `hidden` input (parity-1 buffers; bf16 hi/lo only) ----------
__global__ __launch_bounds__(256) void k_init(
    const float* __restrict__ hid,
    short* __restrict__ h0Hi, short* __restrict__ h0Lo,
    short* __restrict__ h1Hi, short* __restrict__ h1Lo){
  int tid = blockIdx.x*256 + threadIdx.x;   // 32768
  int l = tid >> 14;
  int r = tid & 16383;
  int m = r >> 8;
  int k = (r & 255) << 3;
  const float* s = hid + ((size_t)l*BB + m)*HH + k;
  float v[8];
#pragma unroll
  for(int j=0;j<8;j++) v[j]=s[j];
  short* dh = l ? h1Hi : h0Hi;
  short* dl = l ? h1Lo : h0Lo;
  short hs[8], lsv[8];
#pragma unroll
  for(int j=0;j<8;j++){ hs[j]=f2bf(v[j]); lsv[j]=f2bf(v[j]-bf2f(hs[j])); }
  int mt = m>>4, kc = k>>5, ln = (m&15) | (((k>>3)&3)<<4);
  size_t base = ((size_t)(mt*64 + kc)*64 + ln)*8;
  *(s16x8*)(dh+base) = *(s16x8*)hs;
  *(s16x8*)(dl+base) = *(s16x8*)lsv;
}

// ---------- Phase A: P0 = gather(emb)[8192,2048] @ Wx0^T + b0  (hi/lo 3-product) ----------
__global__ __launch_bounds__(256) void k_gemmA(
    const int* __restrict__ toks, const float* __restrict__ emb,
    const short* __restrict__ WxHi, const short* __restrict__ WxLo,
    const float* __restrict__ b0, float* __restrict__ P0){
  __shared__ short aHi[2][2048];
  __shared__ short aLo[2][2048];
  int bx = blockIdx.x, by = blockIdx.y;
  int tid = threadIdx.x, w = tid>>6, ln = tid&63;
  int srow = w*16 + (ln&15);
  int tok = toks[by*64 + srow];
  const float* rowp = emb + (size_t)tok*2048 + ((ln>>4)<<3);
  int nt = bx*4 + w;
  f32x4 acc[4] = {{0,0,0,0},{0,0,0,0},{0,0,0,0},{0,0,0,0}};
  for(int kc=0;kc<64;kc++){
    int p = kc&1;
    const float4* sp = (const float4*)(rowp + kc*32);
    float4 f0 = sp[0], f1 = sp[1];
    float v[8] = {f0.x,f0.y,f0.z,f0.w,f1.x,f1.y,f1.z,f1.w};
    short hs[8], lsv[8];
#pragma unroll
    for(int j=0;j<8;j++){ hs[j]=f2bf(v[j]); lsv[j]=f2bf(v[j]-bf2f(hs[j])); }
    *(s16x8*)&aHi[p][tid*8] = *(s16x8*)hs;
    *(s16x8*)&aLo[p][tid*8] = *(s16x8*)lsv;
    __syncthreads();
    size_t bidx = ((size_t)(nt*64 + kc)*64 + ln)*8;
    s16x8 bh = *(const s16x8*)(WxHi + bidx);
    s16x8 bl = *(const s16x8*)(WxLo + bidx);
#pragma unroll
    for(int mt=0;mt<4;mt++){
      s16x8 ah = *(const s16x8*)&aHi[p][(mt*64+ln)*8];
      s16x8 al = *(const s16x8*)&aLo[p][(mt*64+ln)*8];
      acc[mt] = MFMA(ah,bh,acc[mt]);
      acc[mt] = MFMA(al,bh,acc[mt]);
      acc[mt] = MFMA(ah,bl,acc[mt]);
    }
  }
  int nl = ln&15;
  int n = bx*64 + w*16 + nl;
  float bias = b0[n];
  int r0 = (ln>>4)*4;
#pragma unroll
  for(int mt=0;mt<4;mt++){
#pragma unroll
    for(int r=0;r<4;r++){
      int m = by*64 + mt*16 + r0 + r;
      P0[(size_t)m*HH + n] = acc[mt][r] + bias;
    }
  }
}

// ---------- persistent recurrence kernel (cooperative) ----------
// 256 blocks x 512 threads. Blocks 0..127: layer0 (Wh hi+lo slice in LDS).
// Blocks 128..255: layer1 (W1 hi slice in LDS, W1 lo streamed, L2-resident).
// Loop t=0..128 with grid.sync(): l0 computes h0(t) (t<128); l1 computes
// h1(t-1) (t>0). h0/h1 double-buffered by parity; h(-1) lives in parity 1.
__global__ __launch_bounds__(512,2) void k_persist(
    const short* __restrict__ WhHi, const short* __restrict__ WhLo,
    const short* __restrict__ W1Hi, const short* __restrict__ W1Lo,
    const float* __restrict__ P0, const float* __restrict__ b1,
    short* __restrict__ H1s,
    short* h0H0, short* h0L0, short* h0H1, short* h0L1,
    short* h1H0, short* h1L0, short* h1H1, short* h1L1,
    float* __restrict__ fin){
  extern __shared__ char smem[];
  short* wlds = (short*)smem;
  float* red  = (float*)(smem + 131072);
  cg::grid_group grid = cg::this_grid();

  short* h0H[2] = {h0H0, h0H1};
  short* h0L[2] = {h0L0, h0L1};
  short* h1H[2] = {h1H0, h1H1};
  short* h1L[2] = {h1L0, h1L1};

  int bid = blockIdx.x;
  int isL1 = bid >= 128;
  int nt = isL1 ? (bid - 128) : bid;
  int tid = threadIdx.x;
  int w = tid>>6, ln = tid&63;
  int wm = w&3, wk = w>>2;

  // stage weights into LDS
  if(!isL1){
    const s16x8* s0 = (const s16x8*)(WhHi + (size_t)nt*32768);
    const s16x8* s1 = (const s16x8*)(WhLo + (size_t)nt*32768);
    s16x8* d0 = (s16x8*)wlds;
    s16x8* d1 = (s16x8*)(wlds + 32768);
#pragma unroll
    for(int i=0;i<8;i++){ d0[tid + i*512] = s0[tid + i*512]; d1[tid + i*512] = s1[tid + i*512]; }
  } else {
    const s16x8* s0 = (const s16x8*)(W1Hi + (size_t)nt*65536);
    s16x8* d0 = (s16x8*)wlds;
#pragma unroll
    for(int i=0;i<16;i++){ d0[tid + i*512] = s0[tid + i*512]; }
  }
  __syncthreads();

  for(int t=0;t<=TT;t++){
    int pa = (t-1)&1;   // parity of t-1 (==1 at t=0)
    int pc = t&1;       // parity of t
    if(!isL1){
      if(t < TT){
        const short* AH = h0H[pa];
        const short* AL = h0L[pa];
        size_t ab = ((size_t)(wm*64 + wk*32)*64 + ln)*8;
        int lb = (wk*32)*512 + ln*8;
        f32x4 aHH={0,0,0,0}, aLH={0,0,0,0}, aHL={0,0,0,0};
        s16x8 ahA = *(const s16x8*)(AH + ab);
        s16x8 alA = *(const s16x8*)(AL + ab);
        s16x8 ahB = *(const s16x8*)(AH + ab + 512);
        s16x8 alB = *(const s16x8*)(AL + ab + 512);
        for(int i=0;i<32;i+=2){
          int i2 = (i+2<32)?(i+2):31, i3 = (i+3<32)?(i+3):31;
          s16x8 pah = *(const s16x8*)(AH + ab + (size_t)i2*512);
          s16x8 pal = *(const s16x8*)(AL + ab + (size_t)i2*512);
          s16x8 qah = *(const s16x8*)(AH + ab + (size_t)i3*512);
          s16x8 qal = *(const s16x8*)(AL + ab + (size_t)i3*512);
          s16x8 bh0 = *(const s16x8*)(wlds + lb + i*512);
          s16x8 bl0 = *(const s16x8*)(wlds + 32768 + lb + i*512);
          s16x8 bh1 = *(const s16x8*)(wlds + lb + (i+1)*512);
          s16x8 bl1 = *(const s16x8*)(wlds + 32768 + lb + (i+1)*512);
          aHH = MFMA(ahA,bh0,aHH); aLH = MFMA(alA,bh0,aLH); aHL = MFMA(ahA,bl0,aHL);
          aHH = MFMA(ahB,bh1,aHH); aLH = MFMA(alB,bh1,aLH); aHL = MFMA(ahB,bl1,aHL);
          ahA = pah; alA = pal; ahB = qah; alB = qal;
        }
        f32x4 sum = aHH + aLH + aHL;
#pragma unroll
        for(int r=0;r<4;r++)
          red[w*256 + ((ln>>4)*4+r)*16 + (ln&15)] = sum[r];
        __syncthreads();
        int m = tid>>3, nl0 = (tid&7)*2;
        const float* P0t = P0 + (size_t)t*131072;
        short* oH = h0H[pc]; short* oL = h0L[pc];
#pragma unroll
        for(int u=0;u<2;u++){
          int nn = nl0 + u, n = nt*16 + nn;
          int wmx = m>>4;
          float s = red[wmx*256 + (m&15)*16 + nn] + red[(wmx+4)*256 + (m&15)*16 + nn];
          float val = tanhf(s + P0t[(size_t)m*HH + n]);
          short hi = f2bf(val), lo = f2bf(val - bf2f(hi));
          int mt = m>>4, kcq = n>>5, ln2 = (m&15) | (((n>>3)&3)<<4), j = n&7;
          size_t idx = ((size_t)(mt*64 + kcq)*64 + ln2)*8 + j;
          oH[idx] = hi; oL[idx] = lo;
          if(t == TT-1) fin[(size_t)m*HH + n] = val;
        }
      }
    } else {
      if(t > 0){
        const short* AH = wk ? h1H[pc] : h0H[pa];
        const short* AL = wk ? h1L[pc] : h0L[pa];
        size_t ab = ((size_t)(wm*64)*64 + ln)*8;
        int kg0 = wk*64;
        const short* BL = W1Lo + (size_t)nt*65536 + kg0*512 + ln*8;
        int lb = kg0*512 + ln*8;
        f32x4 aHH={0,0,0,0}, aLH={0,0,0,0}, aHL={0,0,0,0};
        s16x8 ahA = *(const s16x8*)(AH + ab);
        s16x8 alA = *(const s16x8*)(AL + ab);
        s16x8 blA = *(const s16x8*)(BL);
        s16x8 ahB = *(const s16x8*)(AH + ab + 512);
        s16x8 alB = *(const s16x8*)(AL + ab + 512);
        s16x8 blB = *(const s16x8*)(BL + 512);
        for(int i=0;i<64;i+=2){
          int i2 = (i+2<64)?(i+2):63, i3 = (i+3<64)?(i+3):63;
          s16x8 pah = *(const s16x8*)(AH + ab + (size_t)i2*512);
          s16x8 pal = *(const s16x8*)(AL + ab + (size_t)i2*512);
          s16x8 pbl = *(const s16x8*)(BL + (size_t)i2*512);
          s16x8 qah = *(const s16x8*)(AH + ab + (size_t)i3*512);
          s16x8 qal = *(const s16x8*)(AL + ab + (size_t)i3*512);
          s16x8 qbl = *(const s16x8*)(BL + (size_t)i3*512);
          s16x8 bh0 = *(const s16x8*)(wlds + lb + i*512);
          s16x8 bh1 = *(const s16x8*)(wlds + lb + (i+1)*512);
          aHH = MFMA(ahA,bh0,aHH); aLH = MFMA(alA,bh0,aLH); aHL = MFMA(ahA,blA,aHL);
          aHH = MFMA(ahB,bh1,aHH); aLH = MFMA(alB,bh1,aLH); aHL = MFMA(ahB,blB,aHL);
          ahA = pah; alA = pal; blA = pbl; ahB = qah; alB = qal; blB = qbl;
        }
        f32x4 sum = aHH + aLH + aHL;
#pragma unroll
        for(int r=0;r<4;r++)
          red[w*256 + ((ln>>4)*4+r)*16 + (ln&15)] = sum[r];
        __syncthreads();
        int m = tid>>3, nl0 = (tid&7)*2;
        short* oH = h1H[pa]; short* oL = h1L[pa];
        short* Ht = H1s + (size_t)(t-1)*131072;
#pragma unroll
        for(int u=0;u<2;u++){
          int nn = nl0 + u, n = nt*16 + nn;
          int wmx = m>>4;
          float s = red[wmx*256 + (m&15)*16 + nn] + red[(wmx+4)*256 + (m&15)*16 + nn];
          float val = tanhf(s + b1[n]);
          short hi = f2bf(val), lo = f2bf(val - bf2f(hi));
          int mt = m>>4, kcq = n>>5, ln2 = (m&15) | (((n>>3)&3)<<4), j = n&7;
          size_t idx = ((size_t)(mt*64 + kcq)*64 + ln2)*8 + j;
          oH[idx] = hi; oL[idx] = lo; Ht[idx] = hi;
          if(t == TT) fin[131072 + (size_t)m*HH + n] = val;
        }
      }
    }
    __threadfence();
    if(t < TT) grid.sync();
  }
}

// ---------- Phase C: logits = H1[8192,2048] @ Wout^T + bout (barrier-free 64x64/wave) ----------
__global__ __launch_bounds__(256) void k_gemmC(
    const short* __restrict__ H1s, const short* __restrict__ Wo,
    const float* __restrict__ bout, float* __restrict__ outp){
  int bid = blockIdx.x;                 // 5024 = 8*628 blocks
  int swz = (bid & 7)*628 + (bid >> 3); // XCD-contiguous chunks
  int by = swz / 157;                   // M-panel (256 rows)
  int bx = swz - by*157;                // N-panel (64 cols)
  int tid = threadIdx.x, w = tid>>6, ln = tid&63;
  const short* Ab = H1s + (size_t)(by*16 + w*4)*32768 + ln*8;
  const short* Bb = Wo  + (size_t)(bx*4)*32768 + ln*8;
  f32x4 acc[4][4] = {};
  s16x8 a[4], b[4];
#pragma unroll
  for(int i=0;i<4;i++){
    a[i] = *(const s16x8*)(Ab + (size_t)i*32768);
    b[i] = *(const s16x8*)(Bb + (size_t)i*32768);
  }
  for(int kc=0;kc<64;kc++){
    s16x8 a2[4], b2[4];
    int kn = (kc+1<64)?(kc+1):63;
#pragma unroll
    for(int i=0;i<4;i++){
      a2[i] = *(const s16x8*)(Ab + (size_t)i*32768 + kn*512);
      b2[i] = *(const s16x8*)(Bb + (size_t)i*32768 + kn*512);
    }
#pragma unroll
    for(int i=0;i<4;i++)
#pragma unroll
      for(int j=0;j<4;j++)
        acc[i][j] = MFMA(a[i], b[j], acc[i][j]);
#pragma unroll
    for(int i=0;i<4;i++){ a[i]=a2[i]; b[i]=b2[i]; }
  }
  int nl = ln&15, r0 = (ln>>4)*4;
#pragma unroll
  for(int j=0;j<4;j++){
    int n = (bx*4+j)*16 + nl;
    if(n < VV){
      float bias = bout[n];
#pragma unroll
      for(int i=0;i<4;i++){
        int mb = (by*16 + w*4 + i)*16 + r0;
#pragma unroll
        for(int r=0;r<4;r++)
          outp[(size_t)(mb+r)*VV + n] = acc[i][j][r] + bias;
      }
    }
  }
}

extern "C" void kernel_launch(void* const* d_in, const int* in_sizes, int n_in,
                              void* d_out, int out_size, void* d_ws, size_t ws_size,
                              hipStream_t stream){
  const int*   toks = (const int*)d_in[0];
  const float* hid  = (const float*)d_in[1];
  const float* emb  = (const float*)d_in[2];
  const float* W0   = (const float*)d_in[3];
  const float* b0   = (const float*)d_in[4];
  const float* W1   = (const float*)d_in[5];
  const float* b1   = (const float*)d_in[6];
  const float* Wout = (const float*)d_in[7];
  const float* bout = (const float*)d_in[8];
  float* out = (float*)d_out;

  char* ws = (char*)d_ws;
  size_t off = 0;
  auto take = [&](size_t bytes)->void*{
    void* r = ws + off; off += (bytes + 255) & ~(size_t)255; return r; };

  short* WxHi = (short*)take((size_t)2048*2048*2);
  short* WxLo = (short*)take((size_t)2048*2048*2);
  short* WhHi = (short*)take((size_t)2048*2048*2);
  short* WhLo = (short*)take((size_t)2048*2048*2);
  short* W1Hi = (short*)take((size_t)2048*4096*2);
  short* W1Lo = (short*)take((size_t)2048*4096*2);
  short* Wo   = (short*)take((size_t)VP*2048*2);
  float* P0   = (float*)take((size_t)8192*2048*4);
  short* H1s  = (short*)take((size_t)8192*2048*2);
  short *h0Hi[2], *h0Lo[2], *h1Hi[2], *h1Lo[2];
  for(int i=0;i<2;i++){
    h0Hi[i] = (short*)take((size_t)64*2048*2);
    h0Lo[i] = (short*)take((size_t)64*2048*2);
    h1Hi[i] = (short*)take((size_t)64*2048*2);
    h1Lo[i] = (short*)take((size_t)64*2048*2);
  }

  k_split_w0<<<4096,256,0,stream>>>(W0, WxHi,WxLo,WhHi,WhLo);
  k_split_w1<<<4096,256,0,stream>>>(W1, W1Hi,W1Lo);
  k_conv_wout<<<VP,256,0,stream>>>(Wout, Wo);
  // h0(-1)/h1(-1) live in parity-1 buffers
  k_init<<<128,256,0,stream>>>(hid, h0Hi[1],h0Lo[1], h1Hi[1],h1Lo[1]);
  k_gemmA<<<dim3(32,128),256,0,stream>>>(toks, emb, WxHi, WxLo, b0, P0);

  // persistent recurrence
  hipFuncSetAttribute(reinterpret_cast<const void*>(k_persist),
                      hipFuncAttributeMaxDynamicSharedMemorySize, SMEM_BYTES);
  float* fin = out + (size_t)8192*VV;
  const short *cWhHi=WhHi, *cWhLo=WhLo, *cW1Hi=W1Hi, *cW1Lo=W1Lo;
  const float *cP0=P0, *cb1=b1;
  short *sH1s=H1s;
  short *a0=h0Hi[0], *a1=h0Lo[0], *a2=h0Hi[1], *a3=h0Lo[1];
  short *a4=h1Hi[0], *a5=h1Lo[0], *a6=h1Hi[1], *a7=h1Lo[1];
  void* kargs[] = {
    (void*)&cWhHi, (void*)&cWhLo, (void*)&cW1Hi, (void*)&cW1Lo,
    (void*)&cP0, (void*)&cb1, (void*)&sH1s,
    (void*)&a0, (void*)&a1, (void*)&a2, (void*)&a3,
    (void*)&a4, (void*)&a5, (void*)&a6, (void*)&a7,
    (void*)&fin
  };
  hipLaunchCooperativeKernel(reinterpret_cast<const void*>(k_persist),
                             dim3(256), dim3(512), kargs, SMEM_BYTES, stream);

  k_gemmC<<<5024,256,0,stream>>>(H1s, Wo, bout, out);
}